// Round 7
// baseline (595.461 us; speedup 1.0000x reference)
//
#include <hip/hip_runtime.h>
#include <hip/hip_bf16.h>

#define IN_CH 128
#define OUT_CH 64
#define NEG_SLOPE 0.2f
// Packing: each edge atomically adds (KPACK + p0) to wsum[dst].
// cnt = floor(ws/KPACK), sum_p0 = ws - KPACK*cnt, w1 = cnt - sum_p0.
#define KPACK 1024.5f

#define NBLK 512      // persistent blocks: 2/CU; LDS 39KB -> 4/CU capacity
#define GEMM_BLK 170  // [0,170) gemm role, [170,512) score+edge role

typedef short bf16x8 __attribute__((ext_vector_type(8)));
typedef float f32x4 __attribute__((ext_vector_type(4)));

__device__ __forceinline__ unsigned short f2bf(float f) {
  union { float f; unsigned u; } v;
  v.f = f;
  unsigned r = v.u + 0x7FFF + ((v.u >> 16) & 1);  // RNE
  return (unsigned short)(r >> 16);
}

// Software grid barrier: bar[0]=arrive counter, bar[1]=release flag.
// Device-scope atomics + __threadfence (buffer_wbl2/inv) make prior writes
// visible across XCDs. State is zeroed by hipMemsetAsync before each launch.
__device__ __forceinline__ void bar_arrive(int* bar, int nblk) {
  __syncthreads();  // all waves' stores issued & complete (vmcnt drained)
  if (threadIdx.x == 0) {
    __threadfence();  // flush this XCD's L2 to device scope
    int old = __hip_atomic_fetch_add(&bar[0], 1, __ATOMIC_ACQ_REL,
                                     __HIP_MEMORY_SCOPE_AGENT);
    if (old == nblk - 1)
      __hip_atomic_store(&bar[1], 1, __ATOMIC_RELEASE,
                         __HIP_MEMORY_SCOPE_AGENT);
  }
}
__device__ __forceinline__ void bar_wait(int* bar) {
  if (threadIdx.x == 0) {
    while (!__hip_atomic_load(&bar[1], __ATOMIC_ACQUIRE,
                              __HIP_MEMORY_SCOPE_AGENT))
      __builtin_amdgcn_s_sleep(2);
    __threadfence();  // invalidate stale cached lines before phase reads
  }
  __syncthreads();
}

// ---------------------------------------------------------------------------
// One persistent kernel.
//  gemm role (bid < GEMM_BLK): stage bf16 B^T in LDS; ARRIVE A (no wait);
//    xh = x @ lin_w via mfma_16x16x32_bf16 over row tiles; arrive+wait B.
//  edge role: u = lin_w@att in LDS (redundant, tiny); score si/sj/wself,
//    seed wsum=0; arrive+wait A; edge scatter, ONE fp32 atomic per edge;
//    arrive+wait B.
//  all blocks: decode wsum, out = 0.5*(xh0*w0 + xh1*w1).
// ---------------------------------------------------------------------------
__global__ __launch_bounds__(256) void mega_kernel(
    const float* __restrict__ x, const float* __restrict__ emb,
    const float* __restrict__ lw, const float* __restrict__ att_i,
    const float* __restrict__ att_j, const float* __restrict__ aei,
    const float* __restrict__ aej, const int* __restrict__ esrc,
    const int* __restrict__ edst, float* __restrict__ xh,
    float2* __restrict__ si, float2* __restrict__ sj,
    float* __restrict__ wself, float* __restrict__ wsum,
    float* __restrict__ out, int* __restrict__ bar, int N, int E) {
  __shared__ float uS[512];                // edge role: u_i | u_j
  __shared__ unsigned short Bl[128][136];  // gemm role: bf16 B^T (+8 pad)

  const int bid = blockIdx.x;
  const int tid = threadIdx.x;
  const int wave = tid >> 6;
  const int lane = tid & 63;
  int* barA = bar;
  int* barB = bar + 2;

  if (bid < GEMM_BLK) {
    // ================= gemm role =================
    for (int i = tid; i < IN_CH * IN_CH; i += 256) {
      int k = i >> 7;
      int c = i & 127;
      Bl[c][k] = f2bf(lw[i]);
    }
    bar_arrive(barA, NBLK);  // don't wait: gemm is independent of scores
    __syncthreads();         // Bl visible to block

    const int ntiles = (N + 63) / 64;
    const int ko = (lane >> 4) * 8;
    const int ccol = lane & 15;
    for (int tile = bid; tile < ntiles; tile += GEMM_BLK) {
      const int row0 = tile * 64 + wave * 16;
      int arow = row0 + (lane & 15);
      if (arow >= N) arow = N - 1;  // clamped read; stores guarded
      const float* ap = x + (size_t)arow * IN_CH + ko;
      bf16x8 a[4];
#pragma unroll
      for (int kb = 0; kb < 4; ++kb) {
        float4 f0 = *(const float4*)(ap + kb * 32);
        float4 f1 = *(const float4*)(ap + kb * 32 + 4);
        bf16x8 t;
        t[0] = (short)f2bf(f0.x); t[1] = (short)f2bf(f0.y);
        t[2] = (short)f2bf(f0.z); t[3] = (short)f2bf(f0.w);
        t[4] = (short)f2bf(f1.x); t[5] = (short)f2bf(f1.y);
        t[6] = (short)f2bf(f1.z); t[7] = (short)f2bf(f1.w);
        a[kb] = t;
      }
      const int crow0 = row0 + (lane >> 4) * 4;
#pragma unroll
      for (int nt = 0; nt < 8; ++nt) {
        f32x4 acc = {0.f, 0.f, 0.f, 0.f};
        const bf16x8* bp = (const bf16x8*)&Bl[nt * 16 + ccol][ko];
        acc = __builtin_amdgcn_mfma_f32_16x16x32_bf16(a[0], bp[0], acc, 0, 0, 0);
        acc = __builtin_amdgcn_mfma_f32_16x16x32_bf16(a[1], bp[4], acc, 0, 0, 0);
        acc = __builtin_amdgcn_mfma_f32_16x16x32_bf16(a[2], bp[8], acc, 0, 0, 0);
        acc = __builtin_amdgcn_mfma_f32_16x16x32_bf16(a[3], bp[12], acc, 0, 0, 0);
#pragma unroll
        for (int rr = 0; rr < 4; ++rr) {
          int n = crow0 + rr;
          if (n < N) xh[(size_t)n * IN_CH + nt * 16 + ccol] = acc[rr];
        }
      }
    }
    bar_arrive(barB, NBLK);
    bar_wait(barB);
  } else {
    // ================= score + edge role =================
    const int eb = bid - GEMM_BLK;          // 0..341
    const int EBLK = NBLK - GEMM_BLK;       // 342
    for (int i = tid; i < 512; i += 256) {
      int k = i & 127;
      int h = (i >> 7) & 1;
      const float* att = (i >> 8) ? att_j : att_i;
      float v = 0.f;
#pragma unroll 8
      for (int d = 0; d < 64; ++d)
        v = fmaf(lw[(size_t)k * IN_CH + h * 64 + d], att[h * 64 + d], v);
      uS[i] = v;
    }
    __syncthreads();

    for (int n = eb * 4 + wave; n < N; n += EBLK * 4) {
      float x0 = x[(size_t)n * IN_CH + lane];
      float x1 = x[(size_t)n * IN_CH + 64 + lane];
      float em = emb[(size_t)n * OUT_CH + lane];

      float v_si0 = fmaf(x0, uS[lane], fmaf(x1, uS[64 + lane], em * aei[lane]));
      float v_si1 = fmaf(x0, uS[128 + lane],
                         fmaf(x1, uS[192 + lane], em * aei[64 + lane]));
      float v_sj0 =
          fmaf(x0, uS[256 + lane], fmaf(x1, uS[320 + lane], em * aej[lane]));
      float v_sj1 = fmaf(x0, uS[384 + lane],
                         fmaf(x1, uS[448 + lane], em * aej[64 + lane]));

#pragma unroll
      for (int off = 32; off > 0; off >>= 1) {
        v_si0 += __shfl_xor(v_si0, off, 64);
        v_si1 += __shfl_xor(v_si1, off, 64);
        v_sj0 += __shfl_xor(v_sj0, off, 64);
        v_sj1 += __shfl_xor(v_sj1, off, 64);
      }

      if (lane == 0) {
        si[n] = make_float2(v_si0, v_si1);
        sj[n] = make_float2(v_sj0, v_sj1);
        float a0 = v_si0 + v_sj0;
        float a1 = v_si1 + v_sj1;
        a0 = a0 > 0.f ? a0 : NEG_SLOPE * a0;
        a1 = a1 > 0.f ? a1 : NEG_SLOPE * a1;
        wself[n] = 1.f / (1.f + __expf(a1 - a0));
        wsum[n] = 0.f;
      }
    }

    bar_arrive(barA, NBLK);
    bar_wait(barA);

    const int estride = EBLK * 256;
    for (long e = (long)eb * 256 + tid; e < E; e += estride) {
      int s = esrc[e];
      int d = edst[e];
      float2 aa = si[s];
      float2 bb = sj[d];
      float a0 = aa.x + bb.x;
      float a1 = aa.y + bb.y;
      a0 = a0 > 0.f ? a0 : NEG_SLOPE * a0;
      a1 = a1 > 0.f ? a1 : NEG_SLOPE * a1;
      float p0 = 1.f / (1.f + __expf(a1 - a0));
      unsafeAtomicAdd(&wsum[d], KPACK + p0);
    }

    bar_arrive(barB, NBLK);
    bar_wait(barB);
  }

  // ================= output phase (all blocks) =================
  for (int t = bid * 256 + tid; t < N * 16; t += NBLK * 256) {
    int n = t >> 4;
    int c4 = (t & 15) << 2;
    float wsv = wsum[n];
    float cnt = floorf(wsv * (1.0f / KPACK));
    float s0 = wsv - KPACK * cnt;  // sum of p0 over incoming edges
    float p0s = wself[n];
    float w0 = s0 + p0s;
    float w1 = (cnt - s0) + (1.f - p0s);
    float4 v0 = *(const float4*)&xh[(size_t)n * IN_CH + c4];
    float4 v1 = *(const float4*)&xh[(size_t)n * IN_CH + 64 + c4];
    float4 o;
    o.x = 0.5f * fmaf(v0.x, w0, v1.x * w1);
    o.y = 0.5f * fmaf(v0.y, w0, v1.y * w1);
    o.z = 0.5f * fmaf(v0.z, w0, v1.z * w1);
    o.w = 0.5f * fmaf(v0.w, w0, v1.w * w1);
    *(float4*)&out[(size_t)n * OUT_CH + c4] = o;
  }
}

extern "C" void kernel_launch(void* const* d_in, const int* in_sizes, int n_in,
                              void* d_out, int out_size, void* d_ws,
                              size_t ws_size, hipStream_t stream) {
  const float* x = (const float*)d_in[0];
  const float* emb = (const float*)d_in[1];
  const float* lw = (const float*)d_in[2];
  const float* att_i = (const float*)d_in[3];
  const float* att_j = (const float*)d_in[4];
  const float* aei = (const float*)d_in[5];
  const float* aej = (const float*)d_in[6];
  const int* esrc = (const int*)d_in[7];
  const int* edst = (const int*)d_in[8];
  float* out = (float*)d_out;

  int N = in_sizes[0] / IN_CH;  // 50000
  int E = in_sizes[7];          // 1600000

  char* ws = (char*)d_ws;
  float* xh = (float*)ws;                              // N*128 f32 (25.6 MB)
  float2* si = (float2*)(ws + (size_t)N * IN_CH * 4);  // N float2
  float2* sj = si + N;                                 // N float2
  float* wself = (float*)(sj + N);                     // N f32
  float* wsum = wself + N;                             // N f32
  int* bar = (int*)(wsum + N);                         // 4 ints (barriers)

  hipMemsetAsync(bar, 0, 4 * sizeof(int), stream);
  mega_kernel<<<dim3(NBLK), dim3(256), 0, stream>>>(
      x, emb, lw, att_i, att_j, aei, aej, esrc, edst, xh, si, sj, wself, wsum,
      out, bar, N, E);
}

// Round 9
// 375.148 us; speedup vs baseline: 1.5873x; 1.5873x over previous
//
#include <hip/hip_runtime.h>
#include <hip/hip_bf16.h>

#define IN_CH 128
#define OUT_CH 64
#define NEG_SLOPE 0.2f
// Packing: each edge contributes (KPACK + p0) to its dst's accumulator.
// cnt = floor(ws/KPACK), sum_p0 = ws - KPACK*cnt, w1 = cnt - sum_p0.
#define KPACK 1024.5f

#define BSHIFT 8      // 256 nodes per dst-bucket
#define CHUNK 6250    // edges per bin block (LDS record buffer size)
#define NGEMM 256     // gemm-role blocks in the fused dispatch
#define CAPMAX 9216   // records per bucket region

typedef short bf16x8 __attribute__((ext_vector_type(8)));
typedef float f32x4 __attribute__((ext_vector_type(4)));
typedef unsigned long long u64;

__device__ __forceinline__ unsigned short f2bf(float f) {
  union { float f; unsigned u; } v;
  v.f = f;
  unsigned r = v.u + 0x7FFF + ((v.u >> 16) & 1);  // RNE
  return (unsigned short)(r >> 16);
}

// ---------------------------------------------------------------------------
// Kernel 1 (score): per-node si/sj/wself from x,emb via u = lin_w@att
// (computed redundantly per block in LDS). Seeds wsum=0; block 0 zeroes the
// bucket cursors.
// ---------------------------------------------------------------------------
__global__ __launch_bounds__(256) void score_kernel(
    const float* __restrict__ x, const float* __restrict__ emb,
    const float* __restrict__ lw, const float* __restrict__ att_i,
    const float* __restrict__ att_j, const float* __restrict__ aei,
    const float* __restrict__ aej, float2* __restrict__ si,
    float2* __restrict__ sj, float* __restrict__ wself,
    float* __restrict__ wsum, int* __restrict__ gcur, int N) {
  __shared__ float uS[512];
  const int tid = threadIdx.x;
  const int wave = tid >> 6;
  const int lane = tid & 63;

  if (blockIdx.x == 0) gcur[tid] = 0;  // 256 cursors (nb<=256)

  for (int i = tid; i < 512; i += 256) {
    int k = i & 127;
    int h = (i >> 7) & 1;
    const float* att = (i >> 8) ? att_j : att_i;
    float v = 0.f;
#pragma unroll 8
    for (int d = 0; d < 64; ++d)
      v = fmaf(lw[(size_t)k * IN_CH + h * 64 + d], att[h * 64 + d], v);
    uS[i] = v;
  }
  __syncthreads();

  const int n = blockIdx.x * 4 + wave;
  if (n >= N) return;
  float x0 = x[(size_t)n * IN_CH + lane];
  float x1 = x[(size_t)n * IN_CH + 64 + lane];
  float em = emb[(size_t)n * OUT_CH + lane];

  float v_si0 = fmaf(x0, uS[lane], fmaf(x1, uS[64 + lane], em * aei[lane]));
  float v_si1 =
      fmaf(x0, uS[128 + lane], fmaf(x1, uS[192 + lane], em * aei[64 + lane]));
  float v_sj0 =
      fmaf(x0, uS[256 + lane], fmaf(x1, uS[320 + lane], em * aej[lane]));
  float v_sj1 =
      fmaf(x0, uS[384 + lane], fmaf(x1, uS[448 + lane], em * aej[64 + lane]));

#pragma unroll
  for (int off = 32; off > 0; off >>= 1) {
    v_si0 += __shfl_xor(v_si0, off, 64);
    v_si1 += __shfl_xor(v_si1, off, 64);
    v_sj0 += __shfl_xor(v_sj0, off, 64);
    v_sj1 += __shfl_xor(v_sj1, off, 64);
  }

  if (lane == 0) {
    si[n] = make_float2(v_si0, v_si1);
    sj[n] = make_float2(v_sj0, v_sj1);
    float a0 = v_si0 + v_sj0;
    float a1 = v_si1 + v_sj1;
    a0 = a0 > 0.f ? a0 : NEG_SLOPE * a0;
    a1 = a1 > 0.f ? a1 : NEG_SLOPE * a1;
    wself[n] = 1.f / (1.f + __expf(a1 - a0));
    wsum[n] = 0.f;  // baseline for spill fallback
  }
}

// ---------------------------------------------------------------------------
// Kernel 2 (bin + gemm fused, role-split):
//  bin blocks [0,nbin): counting-sort a 6250-edge chunk by dst>>8 in LDS,
//    reserve per-bucket global runs (few int atomics/block), write records
//    {dst, val} coalesced into bucket regions. Overflow -> device atomic
//    spill into wsum (correct for ANY cap).
//  gemm blocks [nbin, ...): xh = x @ lin_w via mfma_16x16x32_bf16, bf16 B^T
//    staged in LDS (overlaid on the record buffer).
// ---------------------------------------------------------------------------
__global__ __launch_bounds__(256) void bin_gemm_kernel(
    const float* __restrict__ x, const float* __restrict__ lw,
    const int* __restrict__ esrc, const int* __restrict__ edst,
    const float2* __restrict__ si, const float2* __restrict__ sj,
    float* __restrict__ xh, float* __restrict__ wsum,
    u64* __restrict__ brecs, int* __restrict__ gcur, int cap, int nbin, int N,
    int E) {
  __shared__ __align__(16) u64 smem8[CHUNK];  // 50 KB records / B^T overlay
  __shared__ int hist[256];
  __shared__ int scan[256];
  __shared__ int gbase[256];
  __shared__ int cur[256];
  const int bid = blockIdx.x;
  const int tid = threadIdx.x;
  const int wave = tid >> 6;
  const int lane = tid & 63;

  if (bid < nbin) {
    // ================= bin role =================
    u64* recs = smem8;

    hist[tid] = 0;
    __syncthreads();

    const long e0 = (long)bid * CHUNK;
    const int cnt = (int)min((long)CHUNK, (long)E - e0);

    for (int r = tid; r < cnt; r += 256)
      atomicAdd(&hist[edst[e0 + r] >> BSHIFT], 1);
    __syncthreads();

    // Hillis-Steele inclusive scan over 256 buckets
    scan[tid] = hist[tid];
    __syncthreads();
#pragma unroll
    for (int ofs = 1; ofs < 256; ofs <<= 1) {
      int t = (tid >= ofs) ? scan[tid - ofs] : 0;
      __syncthreads();
      scan[tid] += t;
      __syncthreads();
    }
    int excl = scan[tid] - hist[tid];
    __syncthreads();
    scan[tid] = excl;  // exclusive scan
    cur[tid] = excl;
    gbase[tid] = (hist[tid] > 0) ? atomicAdd(&gcur[tid], hist[tid]) : 0;
    __syncthreads();

    // scatter records into LDS grouped by bucket
    for (int r = tid; r < cnt; r += 256) {
      long e = e0 + r;
      int s = esrc[e];
      int d = edst[e];
      float2 aa = si[s];
      float2 bb = sj[d];
      float a0 = aa.x + bb.x;
      float a1 = aa.y + bb.y;
      a0 = a0 > 0.f ? a0 : NEG_SLOPE * a0;
      a1 = a1 > 0.f ? a1 : NEG_SLOPE * a1;
      float p0 = 1.f / (1.f + __expf(a1 - a0));
      float val = KPACK + p0;
      int pos = atomicAdd(&cur[d >> BSHIFT], 1);
      recs[pos] = ((u64)(unsigned)d << 32) | (u64)__float_as_uint(val);
    }
    __syncthreads();

    // write out per bucket: wave w -> buckets w, w+4, ... (coalesced runs)
    for (int b = wave; b < 256; b += 4) {
      int c = hist[b];
      int s0 = scan[b];
      int g0 = gbase[b];
      u64* dp = brecs + (size_t)b * cap;
      for (int r = lane; r < c; r += 64) {
        u64 rec = recs[s0 + r];
        int gofs = g0 + r;
        if (gofs < cap) {
          dp[gofs] = rec;
        } else {  // rare spill: device atomic into wsum
          unsafeAtomicAdd(&wsum[(int)(rec >> 32)],
                          __uint_as_float((unsigned)rec));
        }
      }
    }
  } else {
    // ================= gemm role =================
    typedef unsigned short BlRow[136];
    BlRow* Bl = (BlRow*)smem8;  // 128 x 136 shorts = 34.8 KB (overlay)
    const int g = bid - nbin;

    for (int i = tid; i < IN_CH * IN_CH; i += 256) {
      int k = i >> 7;
      int c = i & 127;
      Bl[c][k] = f2bf(lw[i]);
    }
    __syncthreads();

    const int ntiles = (N + 63) / 64;
    const int ko = (lane >> 4) * 8;
    const int ccol = lane & 15;
    for (int tile = g; tile < ntiles; tile += NGEMM) {
      const int row0 = tile * 64 + wave * 16;
      int arow = row0 + (lane & 15);
      if (arow >= N) arow = N - 1;  // clamped read; stores guarded
      const float* ap = x + (size_t)arow * IN_CH + ko;
      bf16x8 a[4];
#pragma unroll
      for (int kb = 0; kb < 4; ++kb) {
        float4 f0 = *(const float4*)(ap + kb * 32);
        float4 f1 = *(const float4*)(ap + kb * 32 + 4);
        bf16x8 t;
        t[0] = (short)f2bf(f0.x); t[1] = (short)f2bf(f0.y);
        t[2] = (short)f2bf(f0.z); t[3] = (short)f2bf(f0.w);
        t[4] = (short)f2bf(f1.x); t[5] = (short)f2bf(f1.y);
        t[6] = (short)f2bf(f1.z); t[7] = (short)f2bf(f1.w);
        a[kb] = t;
      }
      const int crow0 = row0 + (lane >> 4) * 4;
#pragma unroll
      for (int nt = 0; nt < 8; ++nt) {
        f32x4 acc = {0.f, 0.f, 0.f, 0.f};
        const bf16x8* bp = (const bf16x8*)&Bl[nt * 16 + ccol][ko];
        acc = __builtin_amdgcn_mfma_f32_16x16x32_bf16(a[0], bp[0], acc, 0, 0, 0);
        acc = __builtin_amdgcn_mfma_f32_16x16x32_bf16(a[1], bp[4], acc, 0, 0, 0);
        acc = __builtin_amdgcn_mfma_f32_16x16x32_bf16(a[2], bp[8], acc, 0, 0, 0);
        acc = __builtin_amdgcn_mfma_f32_16x16x32_bf16(a[3], bp[12], acc, 0, 0, 0);
#pragma unroll
        for (int rr = 0; rr < 4; ++rr) {
          int n = crow0 + rr;
          if (n < N) xh[(size_t)n * IN_CH + nt * 16 + ccol] = acc[rr];
        }
      }
    }
  }
}

// ---------------------------------------------------------------------------
// Kernel 3 (reduce + out): block = one dst bucket (1024 threads).
// LDS-accumulate the bucket's records, add wsum baseline (spills), then
// write out = 0.5*(xh0*w0 + xh1*w1) for the bucket's 256 nodes.
// ---------------------------------------------------------------------------
__global__ __launch_bounds__(1024) void reduce_out_kernel(
    const float* __restrict__ xh, const float* __restrict__ wsum,
    const float* __restrict__ wself, const u64* __restrict__ brecs,
    const int* __restrict__ gcur, int cap, float* __restrict__ out, int N) {
  __shared__ float table[256];
  const int b = blockIdx.x;
  const int tid = threadIdx.x;

  if (tid < 256) table[tid] = 0.f;
  __syncthreads();

  const int cnt = min(gcur[b], cap);
  const u64* rp = brecs + (size_t)b * cap;
  for (int r = tid; r < cnt; r += 1024) {
    u64 rec = rp[r];
    atomicAdd(&table[(int)(rec >> 32) & 255], __uint_as_float((unsigned)rec));
  }
  __syncthreads();
  const int n0 = b << BSHIFT;
  if (tid < 256 && n0 + tid < N) table[tid] += wsum[n0 + tid];
  __syncthreads();

  const int nmax = min(256, N - n0);
  for (int t = tid; t < nmax * 16; t += 1024) {
    int ln = t >> 4;
    int n = n0 + ln;
    int c4 = (t & 15) << 2;
    float wsv = table[ln];
    float cntf = floorf(wsv * (1.0f / KPACK));
    float s0 = wsv - KPACK * cntf;
    float p0s = wself[n];
    float w0 = s0 + p0s;
    float w1 = (cntf - s0) + (1.f - p0s);
    float4 v0 = *(const float4*)&xh[(size_t)n * IN_CH + c4];
    float4 v1 = *(const float4*)&xh[(size_t)n * IN_CH + 64 + c4];
    float4 o;
    o.x = 0.5f * fmaf(v0.x, w0, v1.x * w1);
    o.y = 0.5f * fmaf(v0.y, w0, v1.y * w1);
    o.z = 0.5f * fmaf(v0.z, w0, v1.z * w1);
    o.w = 0.5f * fmaf(v0.w, w0, v1.w * w1);
    *(float4*)&out[(size_t)n * OUT_CH + c4] = o;
  }
}

extern "C" void kernel_launch(void* const* d_in, const int* in_sizes, int n_in,
                              void* d_out, int out_size, void* d_ws,
                              size_t ws_size, hipStream_t stream) {
  const float* x = (const float*)d_in[0];
  const float* emb = (const float*)d_in[1];
  const float* lw = (const float*)d_in[2];
  const float* att_i = (const float*)d_in[3];
  const float* att_j = (const float*)d_in[4];
  const float* aei = (const float*)d_in[5];
  const float* aej = (const float*)d_in[6];
  const int* esrc = (const int*)d_in[7];
  const int* edst = (const int*)d_in[8];
  float* out = (float*)d_out;

  int N = in_sizes[0] / IN_CH;  // 50000
  int E = in_sizes[7];          // 1600000
  int nb = (N + 255) >> BSHIFT;        // 196 dst buckets
  int nbin = (E + CHUNK - 1) / CHUNK;  // 256 bin blocks

  char* ws = (char*)d_ws;
  float* xh = (float*)ws;                              // N*128 f32 (25.6 MB)
  float2* si = (float2*)(ws + (size_t)N * IN_CH * 4);  // N float2
  float2* sj = si + N;                                 // N float2
  float* wself = (float*)(sj + N);                     // N f32
  float* wsum = wself + N;                             // N f32
  int* gcur = (int*)(wsum + N);                        // 256 ints
  u64* brecs = (u64*)(gcur + 256);                     // nb * cap records

  size_t fixed = (size_t)((char*)brecs - ws);
  size_t avail = ws_size > fixed ? (ws_size - fixed) / 8 : 0;
  int cap = (int)(avail / (nb > 0 ? nb : 1));
  if (cap > CAPMAX) cap = CAPMAX;
  if (cap < 1024) cap = 1024;  // spill fallback keeps this correct anyway

  score_kernel<<<dim3((N + 3) / 4), dim3(256), 0, stream>>>(
      x, emb, lw, att_i, att_j, aei, aej, si, sj, wself, wsum, gcur, N);
  bin_gemm_kernel<<<dim3(nbin + NGEMM), dim3(256), 0, stream>>>(
      x, lw, esrc, edst, si, sj, xh, wsum, brecs, gcur, cap, nbin, N, E);
  reduce_out_kernel<<<dim3(nb), dim3(1024), 0, stream>>>(
      xh, wsum, wself, brecs, gcur, cap, out, N);
}

// Round 10
// 171.082 us; speedup vs baseline: 3.4805x; 2.1928x over previous
//
#include <hip/hip_runtime.h>
#include <hip/hip_bf16.h>

#define IN_CH 128
#define OUT_CH 64
#define NEG_SLOPE 0.2f
// Packing: each edge contributes (KPACK + p0) to its dst's accumulator.
// cnt = floor(ws/KPACK), sum_p0 = ws - KPACK*cnt, w1 = cnt - sum_p0.
#define KPACK 1024.5f

#define BSHIFT 8      // 256 nodes per dst-bucket
#define CHUNK 6250    // edges per bin block (LDS record buffer size)
#define NGEMM 256     // gemm-role blocks in the fused dispatch
#define CAPMAX 9216   // records per bucket region

typedef short bf16x8 __attribute__((ext_vector_type(8)));
typedef float f32x4 __attribute__((ext_vector_type(4)));
typedef unsigned long long u64;

__device__ __forceinline__ unsigned short f2bf(float f) {
  union { float f; unsigned u; } v;
  v.f = f;
  unsigned r = v.u + 0x7FFF + ((v.u >> 16) & 1);  // RNE
  return (unsigned short)(r >> 16);
}

// ---------------------------------------------------------------------------
// Kernel 0 (prep): 2 blocks. Computes u[which*256 + h*128 + k] =
// sum_d lw[k][h*64+d] * att_{i,j}[h][d] (512 floats). Block 0 also zeroes
// the 256 bucket cursors. Tiny (~64 KB of lw reads, once).
// ---------------------------------------------------------------------------
__global__ __launch_bounds__(256) void prep_kernel(
    const float* __restrict__ lw, const float* __restrict__ att_i,
    const float* __restrict__ att_j, float* __restrict__ u,
    int* __restrict__ gcur) {
  const int tid = threadIdx.x;
  const int which = blockIdx.x;  // 0 -> att_i, 1 -> att_j
  if (which == 0) gcur[tid] = 0;
  const float* att = which ? att_j : att_i;
  int k = tid & 127;
  int h = (tid >> 7) & 1;
  float v = 0.f;
#pragma unroll 8
  for (int d = 0; d < 64; ++d)
    v = fmaf(lw[(size_t)k * IN_CH + h * 64 + d], att[h * 64 + d], v);
  u[which * 256 + h * 128 + k] = v;
}

// ---------------------------------------------------------------------------
// Kernel 1 (score): per-node si/sj/wself from x,emb via precomputed u
// (2 KB, L1-broadcast). Seeds wsum=0. One wave per node.
// ---------------------------------------------------------------------------
__global__ __launch_bounds__(256) void score_kernel(
    const float* __restrict__ x, const float* __restrict__ emb,
    const float* __restrict__ u, const float* __restrict__ aei,
    const float* __restrict__ aej, float2* __restrict__ si,
    float2* __restrict__ sj, float* __restrict__ wself,
    float* __restrict__ wsum, int N) {
  const int tid = threadIdx.x;
  const int wave = tid >> 6;
  const int lane = tid & 63;
  const int n = blockIdx.x * 4 + wave;
  if (n >= N) return;

  float x0 = x[(size_t)n * IN_CH + lane];
  float x1 = x[(size_t)n * IN_CH + 64 + lane];
  float em = emb[(size_t)n * OUT_CH + lane];

  float v_si0 = fmaf(x0, u[lane], fmaf(x1, u[64 + lane], em * aei[lane]));
  float v_si1 =
      fmaf(x0, u[128 + lane], fmaf(x1, u[192 + lane], em * aei[64 + lane]));
  float v_sj0 =
      fmaf(x0, u[256 + lane], fmaf(x1, u[320 + lane], em * aej[lane]));
  float v_sj1 =
      fmaf(x0, u[384 + lane], fmaf(x1, u[448 + lane], em * aej[64 + lane]));

#pragma unroll
  for (int off = 32; off > 0; off >>= 1) {
    v_si0 += __shfl_xor(v_si0, off, 64);
    v_si1 += __shfl_xor(v_si1, off, 64);
    v_sj0 += __shfl_xor(v_sj0, off, 64);
    v_sj1 += __shfl_xor(v_sj1, off, 64);
  }

  if (lane == 0) {
    si[n] = make_float2(v_si0, v_si1);
    sj[n] = make_float2(v_sj0, v_sj1);
    float a0 = v_si0 + v_sj0;
    float a1 = v_si1 + v_sj1;
    a0 = a0 > 0.f ? a0 : NEG_SLOPE * a0;
    a1 = a1 > 0.f ? a1 : NEG_SLOPE * a1;
    wself[n] = 1.f / (1.f + __expf(a1 - a0));
    wsum[n] = 0.f;  // baseline for spill fallback
  }
}

// ---------------------------------------------------------------------------
// Kernel 2 (bin + gemm fused, role-split):
//  bin blocks [0,nbin): counting-sort a 6250-edge chunk by dst>>8 in LDS,
//    reserve per-bucket global runs (few int atomics/block), write records
//    {dst, val} coalesced into bucket regions. Overflow -> device atomic
//    spill into wsum (correct for ANY cap).
//  gemm blocks [nbin, ...): xh = x @ lin_w via mfma_16x16x32_bf16, bf16 B^T
//    staged in LDS (overlaid on the record buffer).
// ---------------------------------------------------------------------------
__global__ __launch_bounds__(256) void bin_gemm_kernel(
    const float* __restrict__ x, const float* __restrict__ lw,
    const int* __restrict__ esrc, const int* __restrict__ edst,
    const float2* __restrict__ si, const float2* __restrict__ sj,
    float* __restrict__ xh, float* __restrict__ wsum,
    u64* __restrict__ brecs, int* __restrict__ gcur, int cap, int nbin, int N,
    int E) {
  __shared__ __align__(16) u64 smem8[CHUNK];  // 50 KB records / B^T overlay
  __shared__ int hist[256];
  __shared__ int scan[256];
  __shared__ int gbase[256];
  __shared__ int cur[256];
  const int bid = blockIdx.x;
  const int tid = threadIdx.x;
  const int wave = tid >> 6;
  const int lane = tid & 63;

  if (bid < nbin) {
    // ================= bin role =================
    u64* recs = smem8;

    hist[tid] = 0;
    __syncthreads();

    const long e0 = (long)bid * CHUNK;
    const int cnt = (int)min((long)CHUNK, (long)E - e0);

    for (int r = tid; r < cnt; r += 256)
      atomicAdd(&hist[edst[e0 + r] >> BSHIFT], 1);
    __syncthreads();

    // Hillis-Steele inclusive scan over 256 buckets
    scan[tid] = hist[tid];
    __syncthreads();
#pragma unroll
    for (int ofs = 1; ofs < 256; ofs <<= 1) {
      int t = (tid >= ofs) ? scan[tid - ofs] : 0;
      __syncthreads();
      scan[tid] += t;
      __syncthreads();
    }
    int excl = scan[tid] - hist[tid];
    __syncthreads();
    scan[tid] = excl;  // exclusive scan
    cur[tid] = excl;
    gbase[tid] = (hist[tid] > 0) ? atomicAdd(&gcur[tid], hist[tid]) : 0;
    __syncthreads();

    // scatter records into LDS grouped by bucket
    for (int r = tid; r < cnt; r += 256) {
      long e = e0 + r;
      int s = esrc[e];
      int d = edst[e];
      float2 aa = si[s];
      float2 bb = sj[d];
      float a0 = aa.x + bb.x;
      float a1 = aa.y + bb.y;
      a0 = a0 > 0.f ? a0 : NEG_SLOPE * a0;
      a1 = a1 > 0.f ? a1 : NEG_SLOPE * a1;
      float p0 = 1.f / (1.f + __expf(a1 - a0));
      float val = KPACK + p0;
      int pos = atomicAdd(&cur[d >> BSHIFT], 1);
      recs[pos] = ((u64)(unsigned)d << 32) | (u64)__float_as_uint(val);
    }
    __syncthreads();

    // write out per bucket: wave w -> buckets w, w+4, ... (coalesced runs)
    for (int b = wave; b < 256; b += 4) {
      int c = hist[b];
      int s0 = scan[b];
      int g0 = gbase[b];
      u64* dp = brecs + (size_t)b * cap;
      for (int r = lane; r < c; r += 64) {
        u64 rec = recs[s0 + r];
        int gofs = g0 + r;
        if (gofs < cap) {
          dp[gofs] = rec;
        } else {  // rare spill: device atomic into wsum
          unsafeAtomicAdd(&wsum[(int)(rec >> 32)],
                          __uint_as_float((unsigned)rec));
        }
      }
    }
  } else {
    // ================= gemm role =================
    typedef unsigned short BlRow[136];
    BlRow* Bl = (BlRow*)smem8;  // 128 x 136 shorts = 34.8 KB (overlay)
    const int g = bid - nbin;

    for (int i = tid; i < IN_CH * IN_CH; i += 256) {
      int k = i >> 7;
      int c = i & 127;
      Bl[c][k] = f2bf(lw[i]);
    }
    __syncthreads();

    const int ntiles = (N + 63) / 64;
    const int ko = (lane >> 4) * 8;
    const int ccol = lane & 15;
    for (int tile = g; tile < ntiles; tile += NGEMM) {
      const int row0 = tile * 64 + wave * 16;
      int arow = row0 + (lane & 15);
      if (arow >= N) arow = N - 1;  // clamped read; stores guarded
      const float* ap = x + (size_t)arow * IN_CH + ko;
      bf16x8 a[4];
#pragma unroll
      for (int kb = 0; kb < 4; ++kb) {
        float4 f0 = *(const float4*)(ap + kb * 32);
        float4 f1 = *(const float4*)(ap + kb * 32 + 4);
        bf16x8 t;
        t[0] = (short)f2bf(f0.x); t[1] = (short)f2bf(f0.y);
        t[2] = (short)f2bf(f0.z); t[3] = (short)f2bf(f0.w);
        t[4] = (short)f2bf(f1.x); t[5] = (short)f2bf(f1.y);
        t[6] = (short)f2bf(f1.z); t[7] = (short)f2bf(f1.w);
        a[kb] = t;
      }
      const int crow0 = row0 + (lane >> 4) * 4;
#pragma unroll
      for (int nt = 0; nt < 8; ++nt) {
        f32x4 acc = {0.f, 0.f, 0.f, 0.f};
        const bf16x8* bp = (const bf16x8*)&Bl[nt * 16 + ccol][ko];
        acc = __builtin_amdgcn_mfma_f32_16x16x32_bf16(a[0], bp[0], acc, 0, 0, 0);
        acc = __builtin_amdgcn_mfma_f32_16x16x32_bf16(a[1], bp[4], acc, 0, 0, 0);
        acc = __builtin_amdgcn_mfma_f32_16x16x32_bf16(a[2], bp[8], acc, 0, 0, 0);
        acc = __builtin_amdgcn_mfma_f32_16x16x32_bf16(a[3], bp[12], acc, 0, 0, 0);
#pragma unroll
        for (int rr = 0; rr < 4; ++rr) {
          int n = crow0 + rr;
          if (n < N) xh[(size_t)n * IN_CH + nt * 16 + ccol] = acc[rr];
        }
      }
    }
  }
}

// ---------------------------------------------------------------------------
// Kernel 3 (reduce + out): block = one dst bucket (1024 threads).
// LDS-accumulate the bucket's records, add wsum baseline (spills), then
// write out = 0.5*(xh0*w0 + xh1*w1) for the bucket's 256 nodes.
// ---------------------------------------------------------------------------
__global__ __launch_bounds__(1024) void reduce_out_kernel(
    const float* __restrict__ xh, const float* __restrict__ wsum,
    const float* __restrict__ wself, const u64* __restrict__ brecs,
    const int* __restrict__ gcur, int cap, float* __restrict__ out, int N) {
  __shared__ float table[256];
  const int b = blockIdx.x;
  const int tid = threadIdx.x;

  if (tid < 256) table[tid] = 0.f;
  __syncthreads();

  const int cnt = min(gcur[b], cap);
  const u64* rp = brecs + (size_t)b * cap;
  for (int r = tid; r < cnt; r += 1024) {
    u64 rec = rp[r];
    atomicAdd(&table[(int)(rec >> 32) & 255], __uint_as_float((unsigned)rec));
  }
  __syncthreads();
  const int n0 = b << BSHIFT;
  if (tid < 256 && n0 + tid < N) table[tid] += wsum[n0 + tid];
  __syncthreads();

  const int nmax = min(256, N - n0);
  for (int t = tid; t < nmax * 16; t += 1024) {
    int ln = t >> 4;
    int n = n0 + ln;
    int c4 = (t & 15) << 2;
    float wsv = table[ln];
    float cntf = floorf(wsv * (1.0f / KPACK));
    float s0 = wsv - KPACK * cntf;
    float p0s = wself[n];
    float w0 = s0 + p0s;
    float w1 = (cntf - s0) + (1.f - p0s);
    float4 v0 = *(const float4*)&xh[(size_t)n * IN_CH + c4];
    float4 v1 = *(const float4*)&xh[(size_t)n * IN_CH + 64 + c4];
    float4 o;
    o.x = 0.5f * fmaf(v0.x, w0, v1.x * w1);
    o.y = 0.5f * fmaf(v0.y, w0, v1.y * w1);
    o.z = 0.5f * fmaf(v0.z, w0, v1.z * w1);
    o.w = 0.5f * fmaf(v0.w, w0, v1.w * w1);
    *(float4*)&out[(size_t)n * OUT_CH + c4] = o;
  }
}

extern "C" void kernel_launch(void* const* d_in, const int* in_sizes, int n_in,
                              void* d_out, int out_size, void* d_ws,
                              size_t ws_size, hipStream_t stream) {
  const float* x = (const float*)d_in[0];
  const float* emb = (const float*)d_in[1];
  const float* lw = (const float*)d_in[2];
  const float* att_i = (const float*)d_in[3];
  const float* att_j = (const float*)d_in[4];
  const float* aei = (const float*)d_in[5];
  const float* aej = (const float*)d_in[6];
  const int* esrc = (const int*)d_in[7];
  const int* edst = (const int*)d_in[8];
  float* out = (float*)d_out;

  int N = in_sizes[0] / IN_CH;  // 50000
  int E = in_sizes[7];          // 1600000
  int nb = (N + 255) >> BSHIFT;        // 196 dst buckets
  int nbin = (E + CHUNK - 1) / CHUNK;  // 256 bin blocks

  char* ws = (char*)d_ws;
  float* xh = (float*)ws;                              // N*128 f32 (25.6 MB)
  float2* si = (float2*)(ws + (size_t)N * IN_CH * 4);  // N float2
  float2* sj = si + N;                                 // N float2
  float* wself = (float*)(sj + N);                     // N f32
  float* wsum = wself + N;                             // N f32
  float* u = wsum + N;                                 // 512 f32
  int* gcur = (int*)(u + 512);                         // 256 ints
  u64* brecs = (u64*)(gcur + 256);                     // nb * cap records

  size_t fixed = (size_t)((char*)brecs - ws);
  size_t avail = ws_size > fixed ? (ws_size - fixed) / 8 : 0;
  int cap = (int)(avail / (nb > 0 ? nb : 1));
  if (cap > CAPMAX) cap = CAPMAX;
  if (cap < 1024) cap = 1024;  // spill fallback keeps this correct anyway

  prep_kernel<<<dim3(2), dim3(256), 0, stream>>>(lw, att_i, att_j, u, gcur);
  score_kernel<<<dim3((N + 3) / 4), dim3(256), 0, stream>>>(
      x, emb, u, aei, aej, si, sj, wself, wsum, N);
  bin_gemm_kernel<<<dim3(nbin + NGEMM), dim3(256), 0, stream>>>(
      x, lw, esrc, edst, si, sj, xh, wsum, brecs, gcur, cap, nbin, N, E);
  reduce_out_kernel<<<dim3(nb), dim3(1024), 0, stream>>>(
      xh, wsum, wself, brecs, gcur, cap, out, N);
}

// Round 11
// 166.968 us; speedup vs baseline: 3.5663x; 1.0246x over previous
//
#include <hip/hip_runtime.h>
#include <hip/hip_bf16.h>

#define IN_CH 128
#define OUT_CH 64
#define NEG_SLOPE 0.2f
// Spill packing (device-atomic fallback only): wsum[d] += KPACK + p0.
#define KPACK 1024.5f

#define BSHIFT 8      // 256 nodes per dst-bucket
#define CHUNK 8192    // edges per bin block (32 KB of u32 records in LDS)
#define NGEMM 256     // gemm-role blocks in the fused dispatch
#define CAPMAX 9216   // records per bucket region (mean 8192 + ~11 sigma)
// 32-bit record: (dlocal << 20) | fix20(p0);  dlocal = dst & 255.
#define FIX20 1048576.0f

typedef short bf16x8 __attribute__((ext_vector_type(8)));
typedef float f32x4 __attribute__((ext_vector_type(4)));
typedef unsigned long long u64;
typedef unsigned int u32;

__device__ __forceinline__ unsigned short f2bf(float f) {
  union { float f; unsigned u; } v;
  v.f = f;
  unsigned r = v.u + 0x7FFF + ((v.u >> 16) & 1);  // RNE
  return (unsigned short)(r >> 16);
}

// ---------------------------------------------------------------------------
// Kernel 0 (prep): 2 blocks. u[which*256 + h*128 + k] =
// sum_d lw[k][h*64+d]*att_{i,j}[h][d]. Block 0 zeroes bucket cursors.
// ---------------------------------------------------------------------------
__global__ __launch_bounds__(256) void prep_kernel(
    const float* __restrict__ lw, const float* __restrict__ att_i,
    const float* __restrict__ att_j, float* __restrict__ u,
    int* __restrict__ gcur) {
  const int tid = threadIdx.x;
  const int which = blockIdx.x;  // 0 -> att_i, 1 -> att_j
  if (which == 0) gcur[tid] = 0;
  const float* att = which ? att_j : att_i;
  int k = tid & 127;
  int h = (tid >> 7) & 1;
  float v = 0.f;
#pragma unroll 8
  for (int d = 0; d < 64; ++d)
    v = fmaf(lw[(size_t)k * IN_CH + h * 64 + d], att[h * 64 + d], v);
  u[which * 256 + h * 128 + k] = v;
}

// ---------------------------------------------------------------------------
// Kernel 1 (score): si/sj/wself from x,emb via precomputed u (L1-hot 2 KB).
// Seeds wsum=0. One wave per node.
// ---------------------------------------------------------------------------
__global__ __launch_bounds__(256) void score_kernel(
    const float* __restrict__ x, const float* __restrict__ emb,
    const float* __restrict__ u, const float* __restrict__ aei,
    const float* __restrict__ aej, float2* __restrict__ si,
    float2* __restrict__ sj, float* __restrict__ wself,
    float* __restrict__ wsum, int N) {
  const int tid = threadIdx.x;
  const int wave = tid >> 6;
  const int lane = tid & 63;
  const int n = blockIdx.x * 4 + wave;
  if (n >= N) return;

  float x0 = x[(size_t)n * IN_CH + lane];
  float x1 = x[(size_t)n * IN_CH + 64 + lane];
  float em = emb[(size_t)n * OUT_CH + lane];

  float v_si0 = fmaf(x0, u[lane], fmaf(x1, u[64 + lane], em * aei[lane]));
  float v_si1 =
      fmaf(x0, u[128 + lane], fmaf(x1, u[192 + lane], em * aei[64 + lane]));
  float v_sj0 =
      fmaf(x0, u[256 + lane], fmaf(x1, u[320 + lane], em * aej[lane]));
  float v_sj1 =
      fmaf(x0, u[384 + lane], fmaf(x1, u[448 + lane], em * aej[64 + lane]));

#pragma unroll
  for (int off = 32; off > 0; off >>= 1) {
    v_si0 += __shfl_xor(v_si0, off, 64);
    v_si1 += __shfl_xor(v_si1, off, 64);
    v_sj0 += __shfl_xor(v_sj0, off, 64);
    v_sj1 += __shfl_xor(v_sj1, off, 64);
  }

  if (lane == 0) {
    si[n] = make_float2(v_si0, v_si1);
    sj[n] = make_float2(v_sj0, v_sj1);
    float a0 = v_si0 + v_sj0;
    float a1 = v_si1 + v_sj1;
    a0 = a0 > 0.f ? a0 : NEG_SLOPE * a0;
    a1 = a1 > 0.f ? a1 : NEG_SLOPE * a1;
    wself[n] = 1.f / (1.f + __expf(a1 - a0));
    wsum[n] = 0.f;  // baseline for spill fallback
  }
}

// ---------------------------------------------------------------------------
// Kernel 2 (bin + gemm fused, role-split):
//  bin blocks [0,nbin): counting-sort an 8192-edge chunk by dst>>8 in LDS
//    (32-bit records), reserve per-bucket global runs, write coalesced.
//    Overflow -> device-atomic spill into wsum (correct for ANY cap).
//  gemm blocks [nbin,...): xh = x @ lin_w via mfma_16x16x32_bf16, bf16 B^T
//    staged in LDS (overlaid on the record buffer).
// LDS: max(32 KB recs, 34.8 KB B^T) + 4 KB tables ~= 39 KB -> 4 blocks/CU.
// ---------------------------------------------------------------------------
__global__ __launch_bounds__(256) void bin_gemm_kernel(
    const float* __restrict__ x, const float* __restrict__ lw,
    const int* __restrict__ esrc, const int* __restrict__ edst,
    const float2* __restrict__ si, const float2* __restrict__ sj,
    float* __restrict__ xh, float* __restrict__ wsum,
    u32* __restrict__ brecs, int* __restrict__ gcur, int cap, int nbin, int N,
    int E) {
  __shared__ __align__(16) u64 smem8[4352];  // 34.8 KB: recs / B^T overlay
  __shared__ int hist[256];
  __shared__ int scan[256];
  __shared__ int gbase[256];
  __shared__ int cur[256];
  const int bid = blockIdx.x;
  const int tid = threadIdx.x;
  const int wave = tid >> 6;
  const int lane = tid & 63;

  if (bid < nbin) {
    // ================= bin role =================
    u32* recs = (u32*)smem8;  // CHUNK u32

    hist[tid] = 0;
    __syncthreads();

    const long e0 = (long)bid * CHUNK;
    const int cnt = (int)min((long)CHUNK, (long)E - e0);

    for (int r = tid; r < cnt; r += 256)
      atomicAdd(&hist[edst[e0 + r] >> BSHIFT], 1);
    __syncthreads();

    // Hillis-Steele inclusive scan over 256 buckets
    scan[tid] = hist[tid];
    __syncthreads();
#pragma unroll
    for (int ofs = 1; ofs < 256; ofs <<= 1) {
      int t = (tid >= ofs) ? scan[tid - ofs] : 0;
      __syncthreads();
      scan[tid] += t;
      __syncthreads();
    }
    int excl = scan[tid] - hist[tid];
    __syncthreads();
    scan[tid] = excl;  // exclusive scan
    cur[tid] = excl;
    gbase[tid] = (hist[tid] > 0) ? atomicAdd(&gcur[tid], hist[tid]) : 0;
    __syncthreads();

    // scatter 32-bit records into LDS grouped by bucket
    for (int r = tid; r < cnt; r += 256) {
      long e = e0 + r;
      int s = esrc[e];
      int d = edst[e];
      float2 aa = si[s];
      float2 bb = sj[d];
      float a0 = aa.x + bb.x;
      float a1 = aa.y + bb.y;
      a0 = a0 > 0.f ? a0 : NEG_SLOPE * a0;
      a1 = a1 > 0.f ? a1 : NEG_SLOPE * a1;
      float p0 = 1.f / (1.f + __expf(a1 - a0));
      u32 fx = (u32)fminf(p0 * FIX20 + 0.5f, 1048575.0f);  // 20-bit
      int pos = atomicAdd(&cur[d >> BSHIFT], 1);
      recs[pos] = ((u32)(d & 255) << 20) | fx;
    }
    __syncthreads();

    // write out per bucket: wave w -> buckets w, w+4, ... (coalesced runs)
    for (int b = wave; b < 256; b += 4) {
      int c = hist[b];
      int s0 = scan[b];
      int g0 = gbase[b];
      u32* dp = brecs + (size_t)b * cap;
      int base = (b << BSHIFT) & ~255;  // bucket's node base (= b*256)
      for (int r = lane; r < c; r += 64) {
        u32 rec = recs[s0 + r];
        int gofs = g0 + r;
        if (gofs < cap) {
          dp[gofs] = rec;
        } else {  // rare spill: device atomic into wsum (float packed)
          float p0 = (float)(rec & 0xFFFFF) * (1.0f / FIX20);
          unsafeAtomicAdd(&wsum[base + (int)(rec >> 20)], KPACK + p0);
        }
      }
    }
  } else {
    // ================= gemm role =================
    typedef unsigned short BlRow[136];
    BlRow* Bl = (BlRow*)smem8;  // 128 x 136 shorts = 34.8 KB (overlay)
    const int g = bid - nbin;

    for (int i = tid; i < IN_CH * IN_CH; i += 256) {
      int k = i >> 7;
      int c = i & 127;
      Bl[c][k] = f2bf(lw[i]);
    }
    __syncthreads();

    const int ntiles = (N + 63) / 64;
    const int ko = (lane >> 4) * 8;
    const int ccol = lane & 15;
    for (int tile = g; tile < ntiles; tile += NGEMM) {
      const int row0 = tile * 64 + wave * 16;
      int arow = row0 + (lane & 15);
      if (arow >= N) arow = N - 1;  // clamped read; stores guarded
      const float* ap = x + (size_t)arow * IN_CH + ko;
      bf16x8 a[4];
#pragma unroll
      for (int kb = 0; kb < 4; ++kb) {
        float4 f0 = *(const float4*)(ap + kb * 32);
        float4 f1 = *(const float4*)(ap + kb * 32 + 4);
        bf16x8 t;
        t[0] = (short)f2bf(f0.x); t[1] = (short)f2bf(f0.y);
        t[2] = (short)f2bf(f0.z); t[3] = (short)f2bf(f0.w);
        t[4] = (short)f2bf(f1.x); t[5] = (short)f2bf(f1.y);
        t[6] = (short)f2bf(f1.z); t[7] = (short)f2bf(f1.w);
        a[kb] = t;
      }
      const int crow0 = row0 + (lane >> 4) * 4;
#pragma unroll
      for (int nt = 0; nt < 8; ++nt) {
        f32x4 acc = {0.f, 0.f, 0.f, 0.f};
        const bf16x8* bp = (const bf16x8*)&Bl[nt * 16 + ccol][ko];
        acc = __builtin_amdgcn_mfma_f32_16x16x32_bf16(a[0], bp[0], acc, 0, 0, 0);
        acc = __builtin_amdgcn_mfma_f32_16x16x32_bf16(a[1], bp[4], acc, 0, 0, 0);
        acc = __builtin_amdgcn_mfma_f32_16x16x32_bf16(a[2], bp[8], acc, 0, 0, 0);
        acc = __builtin_amdgcn_mfma_f32_16x16x32_bf16(a[3], bp[12], acc, 0, 0, 0);
#pragma unroll
        for (int rr = 0; rr < 4; ++rr) {
          int n = crow0 + rr;
          if (n < N) xh[(size_t)n * IN_CH + nt * 16 + ccol] = acc[rr];
        }
      }
    }
  }
}

// ---------------------------------------------------------------------------
// Kernel 3 (reduce + out): block = one dst bucket (1024 threads).
// u64 LDS accumulate: count in hi32, sum(fix20 p0) in lo32 — one atomic per
// record. Add decoded wsum spill baseline, then write the final output.
// ---------------------------------------------------------------------------
__global__ __launch_bounds__(1024) void reduce_out_kernel(
    const float* __restrict__ xh, const float* __restrict__ wsum,
    const float* __restrict__ wself, const u32* __restrict__ brecs,
    const int* __restrict__ gcur, int cap, float* __restrict__ out, int N) {
  __shared__ u64 table[256];
  const int b = blockIdx.x;
  const int tid = threadIdx.x;

  if (tid < 256) table[tid] = 0ull;
  __syncthreads();

  const int cnt = min(gcur[b], cap);
  const u32* rp = brecs + (size_t)b * cap;
  for (int r = tid; r < cnt; r += 1024) {
    u32 rec = rp[r];
    atomicAdd(&table[rec >> 20], (1ull << 32) | (u64)(rec & 0xFFFFF));
  }
  __syncthreads();

  const int n0 = b << BSHIFT;
  const int nmax = min(256, N - n0);
  for (int t = tid; t < nmax * 16; t += 1024) {
    int ln = t >> 4;
    int n = n0 + ln;
    int c4 = (t & 15) << 2;
    u64 acc = table[ln];
    float cnt_i = (float)(u32)(acc >> 32);
    float s0_i = (float)(u32)(acc & 0xFFFFFFFFu) * (1.0f / FIX20);
    // spill baseline (float packed KPACK*cnt + sum_p0)
    float wsv = wsum[n];
    float cnt_s = floorf(wsv * (1.0f / KPACK));
    float s0_s = wsv - KPACK * cnt_s;
    float p0s = wself[n];
    float w0 = s0_i + s0_s + p0s;
    float w1 = (cnt_i + cnt_s - s0_i - s0_s) + (1.f - p0s);
    float4 v0 = *(const float4*)&xh[(size_t)n * IN_CH + c4];
    float4 v1 = *(const float4*)&xh[(size_t)n * IN_CH + 64 + c4];
    float4 o;
    o.x = 0.5f * fmaf(v0.x, w0, v1.x * w1);
    o.y = 0.5f * fmaf(v0.y, w0, v1.y * w1);
    o.z = 0.5f * fmaf(v0.z, w0, v1.z * w1);
    o.w = 0.5f * fmaf(v0.w, w0, v1.w * w1);
    *(float4*)&out[(size_t)n * OUT_CH + c4] = o;
  }
}

extern "C" void kernel_launch(void* const* d_in, const int* in_sizes, int n_in,
                              void* d_out, int out_size, void* d_ws,
                              size_t ws_size, hipStream_t stream) {
  const float* x = (const float*)d_in[0];
  const float* emb = (const float*)d_in[1];
  const float* lw = (const float*)d_in[2];
  const float* att_i = (const float*)d_in[3];
  const float* att_j = (const float*)d_in[4];
  const float* aei = (const float*)d_in[5];
  const float* aej = (const float*)d_in[6];
  const int* esrc = (const int*)d_in[7];
  const int* edst = (const int*)d_in[8];
  float* out = (float*)d_out;

  int N = in_sizes[0] / IN_CH;  // 50000
  int E = in_sizes[7];          // 1600000
  int nb = (N + 255) >> BSHIFT;        // 196 dst buckets
  int nbin = (E + CHUNK - 1) / CHUNK;  // 196 bin blocks

  char* ws = (char*)d_ws;
  float* xh = (float*)ws;                              // N*128 f32 (25.6 MB)
  float2* si = (float2*)(ws + (size_t)N * IN_CH * 4);  // N float2
  float2* sj = si + N;                                 // N float2
  float* wself = (float*)(sj + N);                     // N f32
  float* wsum = wself + N;                             // N f32
  float* u = wsum + N;                                 // 512 f32
  int* gcur = (int*)(u + 512);                         // 256 ints
  u32* brecs = (u32*)(gcur + 256);                     // nb * cap u32 records

  size_t fixed = (size_t)((char*)brecs - ws);
  size_t avail = ws_size > fixed ? (ws_size - fixed) / 4 : 0;
  int cap = (int)(avail / (nb > 0 ? nb : 1));
  if (cap > CAPMAX) cap = CAPMAX;
  if (cap < 1024) cap = 1024;  // spill fallback keeps this correct anyway

  prep_kernel<<<dim3(2), dim3(256), 0, stream>>>(lw, att_i, att_j, u, gcur);
  score_kernel<<<dim3((N + 3) / 4), dim3(256), 0, stream>>>(
      x, emb, u, aei, aej, si, sj, wself, wsum, N);
  bin_gemm_kernel<<<dim3(nbin + NGEMM), dim3(256), 0, stream>>>(
      x, lw, esrc, edst, si, sj, xh, wsum, brecs, gcur, cap, nbin, N, E);
  reduce_out_kernel<<<dim3(nb), dim3(1024), 0, stream>>>(
      xh, wsum, wself, brecs, gcur, cap, out, N);
}

// Round 12
// 163.735 us; speedup vs baseline: 3.6367x; 1.0197x over previous
//
#include <hip/hip_runtime.h>
#include <hip/hip_bf16.h>

#define IN_CH 128
#define OUT_CH 64
#define NEG_SLOPE 0.2f
// Spill packing (device-atomic fallback only): wsum[d] += KPACK + p0.
#define KPACK 1024.5f

#define BSHIFT 8      // 256 nodes per dst-bucket
#define CHUNK 4096    // edges per bin block (16 KB of u32 records in LDS)
#define NGEMM 391     // gemm-role blocks (782 tiles -> 2 each)
#define CAPMAX 9216   // records per bucket region (mean 8192 + ~11 sigma)
// 32-bit record: (dlocal << 20) | fix20(p0);  dlocal = dst & 255.
#define FIX20 1048576.0f

typedef short bf16x8 __attribute__((ext_vector_type(8)));
typedef float f32x4 __attribute__((ext_vector_type(4)));
typedef unsigned long long u64;
typedef unsigned int u32;

__device__ __forceinline__ unsigned short f2bf(float f) {
  union { float f; unsigned u; } v;
  v.f = f;
  unsigned r = v.u + 0x7FFF + ((v.u >> 16) & 1);  // RNE
  return (unsigned short)(r >> 16);
}

// ---------------------------------------------------------------------------
// Kernel 0 (prep): 66 blocks.
//  bid<64: lwt[c][k] = bf16(lw[k][c]) (transposed 32 KB bf16 table).
//  bid 64/65: u_i / u_j (512 floats). bid 0 also zeroes bucket cursors.
// ---------------------------------------------------------------------------
__global__ __launch_bounds__(256) void prep_kernel(
    const float* __restrict__ lw, const float* __restrict__ att_i,
    const float* __restrict__ att_j, unsigned short* __restrict__ lwt,
    float* __restrict__ u, int* __restrict__ gcur) {
  const int bid = blockIdx.x;
  const int tid = threadIdx.x;
  if (bid == 0) gcur[tid] = 0;
  if (bid < 64) {
    int idx = bid * 256 + tid;  // 0..16383
    int k = idx >> 7;
    int c = idx & 127;
    lwt[(size_t)c * IN_CH + k] = f2bf(lw[idx]);
  } else {
    int which = bid - 64;  // 0 -> att_i, 1 -> att_j
    const float* att = which ? att_j : att_i;
    int k = tid & 127;
    int h = (tid >> 7) & 1;
    float v = 0.f;
#pragma unroll 8
    for (int d = 0; d < 64; ++d)
      v = fmaf(lw[(size_t)k * IN_CH + h * 64 + d], att[h * 64 + d], v);
    u[which * 256 + h * 128 + k] = v;
  }
}

// ---------------------------------------------------------------------------
// Kernel 1 (score): si/sj/wself from x,emb via precomputed u (L1-hot 2 KB).
// Seeds wsum=0. One wave per node.
// ---------------------------------------------------------------------------
__global__ __launch_bounds__(256) void score_kernel(
    const float* __restrict__ x, const float* __restrict__ emb,
    const float* __restrict__ u, const float* __restrict__ aei,
    const float* __restrict__ aej, float2* __restrict__ si,
    float2* __restrict__ sj, float* __restrict__ wself,
    float* __restrict__ wsum, int N) {
  const int tid = threadIdx.x;
  const int wave = tid >> 6;
  const int lane = tid & 63;
  const int n = blockIdx.x * 4 + wave;
  if (n >= N) return;

  float x0 = x[(size_t)n * IN_CH + lane];
  float x1 = x[(size_t)n * IN_CH + 64 + lane];
  float em = emb[(size_t)n * OUT_CH + lane];

  float v_si0 = fmaf(x0, u[lane], fmaf(x1, u[64 + lane], em * aei[lane]));
  float v_si1 =
      fmaf(x0, u[128 + lane], fmaf(x1, u[192 + lane], em * aei[64 + lane]));
  float v_sj0 =
      fmaf(x0, u[256 + lane], fmaf(x1, u[320 + lane], em * aej[lane]));
  float v_sj1 =
      fmaf(x0, u[384 + lane], fmaf(x1, u[448 + lane], em * aej[64 + lane]));

#pragma unroll
  for (int off = 32; off > 0; off >>= 1) {
    v_si0 += __shfl_xor(v_si0, off, 64);
    v_si1 += __shfl_xor(v_si1, off, 64);
    v_sj0 += __shfl_xor(v_sj0, off, 64);
    v_sj1 += __shfl_xor(v_sj1, off, 64);
  }

  if (lane == 0) {
    si[n] = make_float2(v_si0, v_si1);
    sj[n] = make_float2(v_sj0, v_sj1);
    float a0 = v_si0 + v_sj0;
    float a1 = v_si1 + v_sj1;
    a0 = a0 > 0.f ? a0 : NEG_SLOPE * a0;
    a1 = a1 > 0.f ? a1 : NEG_SLOPE * a1;
    wself[n] = 1.f / (1.f + __expf(a1 - a0));
    wsum[n] = 0.f;  // baseline for spill fallback
  }
}

// ---------------------------------------------------------------------------
// Kernel 2 (bin + gemm fused, role-split). LDS = 20 KB -> 8 blocks/CU.
//  bin blocks [0,nbin): counting-sort a 4096-edge chunk by dst>>8 into LDS
//    (u32 records), reserve global runs, write ALL records coalesced via
//    binary search over the scan array. Overflow -> atomic spill into wsum.
//  gemm blocks [nbin,...): xh = x @ lin_w via mfma_16x16x32_bf16, B^T read
//    directly from the global bf16 lwt table (L1-resident 32 KB, no LDS).
// ---------------------------------------------------------------------------
__global__ __launch_bounds__(256) void bin_gemm_kernel(
    const float* __restrict__ x, const unsigned short* __restrict__ lwt,
    const int* __restrict__ esrc, const int* __restrict__ edst,
    const float2* __restrict__ si, const float2* __restrict__ sj,
    float* __restrict__ xh, float* __restrict__ wsum,
    u32* __restrict__ brecs, int* __restrict__ gcur, int cap, int nbin, int N,
    int E) {
  __shared__ u32 recs[CHUNK];  // 16 KB
  __shared__ int hist[256];
  __shared__ int scan[256];
  __shared__ int gbase[256];
  __shared__ int cur[256];
  const int bid = blockIdx.x;
  const int tid = threadIdx.x;
  const int wave = tid >> 6;
  const int lane = tid & 63;

  if (bid < nbin) {
    // ================= bin role =================
    hist[tid] = 0;
    __syncthreads();

    const long e0 = (long)bid * CHUNK;
    const int cnt = (int)min((long)CHUNK, (long)E - e0);

    for (int r = tid; r < cnt; r += 256)
      atomicAdd(&hist[edst[e0 + r] >> BSHIFT], 1);
    __syncthreads();

    // Hillis-Steele inclusive scan over 256 buckets
    scan[tid] = hist[tid];
    __syncthreads();
#pragma unroll
    for (int ofs = 1; ofs < 256; ofs <<= 1) {
      int t = (tid >= ofs) ? scan[tid - ofs] : 0;
      __syncthreads();
      scan[tid] += t;
      __syncthreads();
    }
    int excl = scan[tid] - hist[tid];
    __syncthreads();
    scan[tid] = excl;  // exclusive scan
    cur[tid] = excl;
    gbase[tid] = (hist[tid] > 0) ? atomicAdd(&gcur[tid], hist[tid]) : 0;
    __syncthreads();

    // scatter 32-bit records into LDS grouped by bucket
    for (int r = tid; r < cnt; r += 256) {
      long e = e0 + r;
      int s = esrc[e];
      int d = edst[e];
      float2 aa = si[s];
      float2 bb = sj[d];
      float a0 = aa.x + bb.x;
      float a1 = aa.y + bb.y;
      a0 = a0 > 0.f ? a0 : NEG_SLOPE * a0;
      a1 = a1 > 0.f ? a1 : NEG_SLOPE * a1;
      float p0 = 1.f / (1.f + __expf(a1 - a0));
      u32 fx = (u32)fminf(p0 * FIX20 + 0.5f, 1048575.0f);  // 20-bit
      int pos = atomicAdd(&cur[d >> BSHIFT], 1);
      recs[pos] = ((u32)(d & 255) << 20) | fx;
    }
    __syncthreads();

    // write out ALL records, coalesced; bucket found by binary search.
    for (int p = tid; p < cnt; p += 256) {
      int lo = 0, hi = 255;
#pragma unroll
      for (int it = 0; it < 8; ++it) {
        int mid = (lo + hi + 1) >> 1;
        if (scan[mid] <= p) lo = mid; else hi = mid - 1;
      }
      int b = lo;
      int gofs = gbase[b] + (p - scan[b]);
      u32 rec = recs[p];
      if (gofs < cap) {
        brecs[(size_t)b * cap + gofs] = rec;
      } else {  // rare spill: device atomic into wsum (float packed)
        float p0 = (float)(rec & 0xFFFFF) * (1.0f / FIX20);
        unsafeAtomicAdd(&wsum[(b << BSHIFT) + (int)(rec >> 20)], KPACK + p0);
      }
    }
  } else {
    // ================= gemm role (no LDS) =================
    const int g = bid - nbin;
    const int ntiles = (N + 63) / 64;
    const int ko = (lane >> 4) * 8;
    const int ccol = lane & 15;
    for (int tile = g; tile < ntiles; tile += NGEMM) {
      const int row0 = tile * 64 + wave * 16;
      int arow = row0 + (lane & 15);
      if (arow >= N) arow = N - 1;  // clamped read; stores guarded
      const float* ap = x + (size_t)arow * IN_CH + ko;
      bf16x8 a[4];
#pragma unroll
      for (int kb = 0; kb < 4; ++kb) {
        float4 f0 = *(const float4*)(ap + kb * 32);
        float4 f1 = *(const float4*)(ap + kb * 32 + 4);
        bf16x8 t;
        t[0] = (short)f2bf(f0.x); t[1] = (short)f2bf(f0.y);
        t[2] = (short)f2bf(f0.z); t[3] = (short)f2bf(f0.w);
        t[4] = (short)f2bf(f1.x); t[5] = (short)f2bf(f1.y);
        t[6] = (short)f2bf(f1.z); t[7] = (short)f2bf(f1.w);
        a[kb] = t;
      }
      const int crow0 = row0 + (lane >> 4) * 4;
#pragma unroll
      for (int nt = 0; nt < 8; ++nt) {
        f32x4 acc = {0.f, 0.f, 0.f, 0.f};
        const bf16x8* bp =
            (const bf16x8*)(lwt + (size_t)(nt * 16 + ccol) * IN_CH + ko);
        acc = __builtin_amdgcn_mfma_f32_16x16x32_bf16(a[0], bp[0], acc, 0, 0, 0);
        acc = __builtin_amdgcn_mfma_f32_16x16x32_bf16(a[1], bp[4], acc, 0, 0, 0);
        acc = __builtin_amdgcn_mfma_f32_16x16x32_bf16(a[2], bp[8], acc, 0, 0, 0);
        acc = __builtin_amdgcn_mfma_f32_16x16x32_bf16(a[3], bp[12], acc, 0, 0, 0);
#pragma unroll
        for (int rr = 0; rr < 4; ++rr) {
          int n = crow0 + rr;
          if (n < N) xh[(size_t)n * IN_CH + nt * 16 + ccol] = acc[rr];
        }
      }
    }
  }
}

// ---------------------------------------------------------------------------
// Kernel 3 (reduce + out): block = one dst bucket (1024 threads).
// u64 LDS accumulate: count in hi32, sum(fix20 p0) in lo32 — one atomic per
// record. Add decoded wsum spill baseline, then write the final output.
// ---------------------------------------------------------------------------
__global__ __launch_bounds__(1024) void reduce_out_kernel(
    const float* __restrict__ xh, const float* __restrict__ wsum,
    const float* __restrict__ wself, const u32* __restrict__ brecs,
    const int* __restrict__ gcur, int cap, float* __restrict__ out, int N) {
  __shared__ u64 table[256];
  const int b = blockIdx.x;
  const int tid = threadIdx.x;

  if (tid < 256) table[tid] = 0ull;
  __syncthreads();

  const int cnt = min(gcur[b], cap);
  const u32* rp = brecs + (size_t)b * cap;
  for (int r = tid; r < cnt; r += 1024) {
    u32 rec = rp[r];
    atomicAdd(&table[rec >> 20], (1ull << 32) | (u64)(rec & 0xFFFFF));
  }
  __syncthreads();

  const int n0 = b << BSHIFT;
  const int nmax = min(256, N - n0);
  for (int t = tid; t < nmax * 16; t += 1024) {
    int ln = t >> 4;
    int n = n0 + ln;
    int c4 = (t & 15) << 2;
    u64 acc = table[ln];
    float cnt_i = (float)(u32)(acc >> 32);
    float s0_i = (float)(u32)(acc & 0xFFFFFFFFu) * (1.0f / FIX20);
    // spill baseline (float packed KPACK*cnt + sum_p0)
    float wsv = wsum[n];
    float cnt_s = floorf(wsv * (1.0f / KPACK));
    float s0_s = wsv - KPACK * cnt_s;
    float p0s = wself[n];
    float w0 = s0_i + s0_s + p0s;
    float w1 = (cnt_i + cnt_s - s0_i - s0_s) + (1.f - p0s);
    float4 v0 = *(const float4*)&xh[(size_t)n * IN_CH + c4];
    float4 v1 = *(const float4*)&xh[(size_t)n * IN_CH + 64 + c4];
    float4 o;
    o.x = 0.5f * fmaf(v0.x, w0, v1.x * w1);
    o.y = 0.5f * fmaf(v0.y, w0, v1.y * w1);
    o.z = 0.5f * fmaf(v0.z, w0, v1.z * w1);
    o.w = 0.5f * fmaf(v0.w, w0, v1.w * w1);
    *(float4*)&out[(size_t)n * OUT_CH + c4] = o;
  }
}

extern "C" void kernel_launch(void* const* d_in, const int* in_sizes, int n_in,
                              void* d_out, int out_size, void* d_ws,
                              size_t ws_size, hipStream_t stream) {
  const float* x = (const float*)d_in[0];
  const float* emb = (const float*)d_in[1];
  const float* lw = (const float*)d_in[2];
  const float* att_i = (const float*)d_in[3];
  const float* att_j = (const float*)d_in[4];
  const float* aei = (const float*)d_in[5];
  const float* aej = (const float*)d_in[6];
  const int* esrc = (const int*)d_in[7];
  const int* edst = (const int*)d_in[8];
  float* out = (float*)d_out;

  int N = in_sizes[0] / IN_CH;  // 50000
  int E = in_sizes[7];          // 1600000
  int nb = (N + 255) >> BSHIFT;        // 196 dst buckets
  int nbin = (E + CHUNK - 1) / CHUNK;  // 391 bin blocks

  char* ws = (char*)d_ws;
  float* xh = (float*)ws;                              // N*128 f32 (25.6 MB)
  float2* si = (float2*)(ws + (size_t)N * IN_CH * 4);  // N float2
  float2* sj = si + N;                                 // N float2
  float* wself = (float*)(sj + N);                     // N f32
  float* wsum = wself + N;                             // N f32
  float* u = wsum + N;                                 // 512 f32
  unsigned short* lwt = (unsigned short*)(u + 512);    // 16384 bf16 (32 KB)
  int* gcur = (int*)(lwt + 16384);                     // 256 ints
  u32* brecs = (u32*)(gcur + 256);                     // nb * cap u32 records

  size_t fixed = (size_t)((char*)brecs - ws);
  size_t avail = ws_size > fixed ? (ws_size - fixed) / 4 : 0;
  int cap = (int)(avail / (nb > 0 ? nb : 1));
  if (cap > CAPMAX) cap = CAPMAX;
  if (cap < 1024) cap = 1024;  // spill fallback keeps this correct anyway

  prep_kernel<<<dim3(66), dim3(256), 0, stream>>>(lw, att_i, att_j, lwt, u,
                                                  gcur);
  score_kernel<<<dim3((N + 3) / 4), dim3(256), 0, stream>>>(
      x, emb, u, aei, aej, si, sj, wself, wsum, N);
  bin_gemm_kernel<<<dim3(nbin + NGEMM), dim3(256), 0, stream>>>(
      x, lwt, esrc, edst, si, sj, xh, wsum, brecs, gcur, cap, nbin, N, E);
  reduce_out_kernel<<<dim3(nb), dim3(1024), 0, stream>>>(
      xh, wsum, wself, brecs, gcur, cap, out, N);
}